// Round 3
// baseline (678.556 us; speedup 1.0000x reference)
//
#include <hip/hip_runtime.h>

// Problem constants
#define B_   4
#define L_   4096
#define D_   1024
#define ROWS (B_ * L_)     // 16384
#define K2   (2 * D_)      // 2048
#define BLD  (ROWS * D_)   // 16777216
#define CH   128           // chunk length for scan
#define NC   32            // chunks per sequence (CH*NC == L_)
#define MAGIC 0x5CA7F00Du  // lookback-ready flag value (ws poison is 0xAAAAAAAA)

typedef __attribute__((ext_vector_type(8))) short s8v;   // 8 x bf16 (4 VGPRs)
typedef __attribute__((ext_vector_type(4))) float f4v;   // 4 x f32 acc

// fp32 -> bf16, round-to-nearest-even
__device__ __forceinline__ unsigned short f2bf(float f) {
    unsigned int u = __float_as_uint(f);
    u += 0x7FFFu + ((u >> 16) & 1u);
    return (unsigned short)(u >> 16);
}

__device__ __forceinline__ float sigmoidf_(float v) {
    return 1.0f / (1.0f + __expf(-v));
}

// async 16B global -> LDS (wave-uniform LDS base + lane*16)
__device__ __forceinline__ void llds16(const void* g, void* l) {
    __builtin_amdgcn_global_load_lds(
        (const __attribute__((address_space(1))) unsigned int*)(g),
        (__attribute__((address_space(3))) unsigned int*)(l),
        16, 0, 0);
}

// ---------------- fused scan (decoupled lookback) + W convert ----------------
// Blocks [0,512): scan. bid = b*128 + c*4 + dblk. Each thread owns one d
// column of one 128-row chunk; x held in registers (read ONCE).
// Blocks [512, 2560): convert W to bf16 with interleaved K layout:
//   Wbf[e][2k] = W[e][k], Wbf[e][2k+1] = W[e][1024+k].
// A gets the same K interleave (col 2d = x, 2d+1 = avg), so the GEMM result
// is unchanged while the scan's bf16 store becomes one coalesced dword.
__global__ __launch_bounds__(256) void scan_conv(
        const float* __restrict__ x, const float* __restrict__ W,
        float* __restrict__ avg_out, unsigned int* __restrict__ Apk,
        ushort4* __restrict__ Wbf, float* __restrict__ part,
        unsigned int* __restrict__ flag) {
    const int bid = blockIdx.x;
    const int t   = threadIdx.x;

    if (bid < 512) {
        const int dblk = bid & 3;
        const int c    = (bid >> 2) & 31;
        const int b    = bid >> 7;
        const int d    = dblk * 256 + t;
        const size_t row0 = (size_t)b * L_ + (size_t)c * CH;
        const float* p = x + row0 * D_ + d;

        // Phase 1: load chunk into registers, compute chunk sum
        float xv[CH];
        float s = 0.f;
#pragma unroll
        for (int i = 0; i < CH; ++i) { xv[i] = p[(size_t)i * D_]; s += xv[i]; }

        // Publish chunk sum (vector payload + flag). Every thread fences its
        // own store; barrier; then one thread raises the flag.
        part[bid * 256 + t] = s;
        __threadfence();
        __syncthreads();
        if (t == 0)
            __hip_atomic_store(&flag[bid], MAGIC, __ATOMIC_RELEASE, __HIP_MEMORY_SCOPE_AGENT);

        // Lookback: sum all predecessor chunks of this (b, dblk) column.
        // Dependency is strictly bid-decreasing -> deadlock-free.
        float prefix = 0.f;
        for (int cp = c - 1; cp >= 0; --cp) {
            const int pb = bid - 4 * (c - cp);
            while (__hip_atomic_load(&flag[pb], __ATOMIC_ACQUIRE, __HIP_MEMORY_SCOPE_AGENT) != MAGIC)
                __builtin_amdgcn_s_sleep(1);
            prefix += part[pb * 256 + t];
        }

        // Phase 2: running sum, write avg fp32 + packed bf16 (x|avg) dword.
        __shared__ float inv[CH];
        if (t < CH) inv[t] = 1.0f / (float)(c * CH + t + 1);
        __syncthreads();
        float run = prefix;
#pragma unroll
        for (int i = 0; i < CH; ++i) {
            const size_t row = row0 + i;
            run += xv[i];
            const float av = run * inv[i];
            avg_out[row * D_ + d] = av;
            const unsigned int packed =
                (unsigned int)f2bf(xv[i]) | ((unsigned int)f2bf(av) << 16);
            Apk[row * (K2 / 2) + d] = packed;   // columns (2d, 2d+1)
        }
    } else {
        // W convert: 2048 blocks x 256 threads, one k4-group (4 col-pairs) each
        const int idx = (bid - 512) * 256 + t;      // [0, 524288)
        const int e   = idx >> 8;
        const int k4  = idx & 255;
        const float4 v1 = ((const float4*)W)[(size_t)e * 512 + k4];        // cols 4k4..   (x-half)
        const float4 v2 = ((const float4*)W)[(size_t)e * 512 + 256 + k4];  // cols 1024+.. (avg-half)
        ushort4 o0, o1;
        o0.x = f2bf(v1.x); o0.y = f2bf(v2.x); o0.z = f2bf(v1.y); o0.w = f2bf(v2.y);
        o1.x = f2bf(v1.z); o1.y = f2bf(v2.z); o1.z = f2bf(v1.w); o1.w = f2bf(v2.w);
        Wbf[(size_t)e * 512 + 2 * k4]     = o0;    // ushort4 units: row stride 512
        Wbf[(size_t)e * 512 + 2 * k4 + 1] = o1;
    }
}

// ---------------- fused GEMM + gating (N-pair) ----------------
// Each block computes the 128x128 tiles for columns [col0,col0+128) of BOTH
// gate halves (e and e+1024), then applies sigmoid gating in-register and
// writes the final gating_outputs tile. 32 MFMAs per barrier pair.
__global__ __launch_bounds__(256, 2) void gemm_gated(
        const unsigned short* __restrict__ Abf, const unsigned short* __restrict__ Wbf,
        const float* __restrict__ x, const float* __restrict__ avg,
        const float* __restrict__ bg, float* __restrict__ out) {
    __shared__ __attribute__((aligned(16))) unsigned short sA [128 * 32];
    __shared__ __attribute__((aligned(16))) unsigned short sB0[128 * 32];
    __shared__ __attribute__((aligned(16))) unsigned short sB1[128 * 32];

    const int t    = threadIdx.x;
    const int w    = t >> 6;
    const int lane = t & 63;
    const int bid  = blockIdx.x;
    const int tileN = bid & 7, tileM = bid >> 3;     // 8 N-pairs x 128 M-tiles
    const int row0 = tileM * 128, col0 = tileN * 128;
    const int wm = w >> 1, wn = w & 1;
    const int quad = lane >> 4, lcol = lane & 15;

    f4v acc0[4][4], acc1[4][4];
#pragma unroll
    for (int i = 0; i < 4; ++i)
#pragma unroll
        for (int j = 0; j < 4; ++j)
#pragma unroll
            for (int r = 0; r < 4; ++r) { acc0[i][j][r] = 0.f; acc1[i][j][r] = 0.f; }

    // staging: 512 chunks of 16B per 128x32 tile; chunk c -> row c>>2, col (c&3)*8
    const int c0 = t, c1 = 256 + t;
    const unsigned short* gA0 = Abf + ((size_t)(row0 + (c0 >> 2)) * K2 + (c0 & 3) * 8);
    const unsigned short* gA1 = Abf + ((size_t)(row0 + (c1 >> 2)) * K2 + (c1 & 3) * 8);
    const unsigned short* gB0a = Wbf + ((size_t)(col0 + (c0 >> 2)) * K2 + (c0 & 3) * 8);
    const unsigned short* gB0b = Wbf + ((size_t)(col0 + (c1 >> 2)) * K2 + (c1 & 3) * 8);
    const unsigned short* gB1a = Wbf + ((size_t)(col0 + 1024 + (c0 >> 2)) * K2 + (c0 & 3) * 8);
    const unsigned short* gB1b = Wbf + ((size_t)(col0 + 1024 + (c1 >> 2)) * K2 + (c1 & 3) * 8);
    unsigned short* lA0  = &sA [w * 512];
    unsigned short* lA1  = &sA [2048 + w * 512];
    unsigned short* lB0a = &sB0[w * 512];
    unsigned short* lB0b = &sB0[2048 + w * 512];
    unsigned short* lB1a = &sB1[w * 512];
    unsigned short* lB1b = &sB1[2048 + w * 512];

    for (int k0 = 0; k0 < K2; k0 += 32) {
        __syncthreads();                       // protect LDS from overwrite
        llds16(gA0  + k0, lA0);
        llds16(gA1  + k0, lA1);
        llds16(gB0a + k0, lB0a);
        llds16(gB0b + k0, lB0b);
        llds16(gB1a + k0, lB1a);
        llds16(gB1b + k0, lB1b);
        __syncthreads();                       // drains vmcnt -> data ready

        s8v af[4], bf0[4], bf1[4];
#pragma unroll
        for (int i = 0; i < 4; ++i)
            af[i] = *(const s8v*)&sA[(wm * 64 + i * 16 + lcol) * 32 + quad * 8];
#pragma unroll
        for (int j = 0; j < 4; ++j) {
            bf0[j] = *(const s8v*)&sB0[(wn * 64 + j * 16 + lcol) * 32 + quad * 8];
            bf1[j] = *(const s8v*)&sB1[(wn * 64 + j * 16 + lcol) * 32 + quad * 8];
        }
#pragma unroll
        for (int i = 0; i < 4; ++i)
#pragma unroll
            for (int j = 0; j < 4; ++j) {
                acc0[i][j] = __builtin_amdgcn_mfma_f32_16x16x32_bf16(af[i], bf0[j], acc0[i][j], 0, 0, 0);
                acc1[i][j] = __builtin_amdgcn_mfma_f32_16x16x32_bf16(af[i], bf1[j], acc1[i][j], 0, 0, 0);
            }
    }

    // Epilogue: gating in-register. C/D layout: col = lane&15, row = quad*4 + reg
    float b1v[4], b2v[4];
#pragma unroll
    for (int j = 0; j < 4; ++j) {
        int cc = col0 + wn * 64 + j * 16 + lcol;
        b1v[j] = bg[cc];
        b2v[j] = bg[1024 + cc];
    }
#pragma unroll
    for (int i = 0; i < 4; ++i) {
#pragma unroll
        for (int j = 0; j < 4; ++j) {
            int rr = row0 + wm * 64 + i * 16 + quad * 4;
            int cc = col0 + wn * 64 + j * 16 + lcol;
#pragma unroll
            for (int r = 0; r < 4; ++r) {
                size_t off = (size_t)(rr + r) * D_ + cc;
                float gi = sigmoidf_(acc0[i][j][r] + b1v[j]);
                float gf = sigmoidf_(acc1[i][j][r] + b2v[j]);
                out[off] = gi * x[off] + gf * avg[off];
            }
        }
    }
}

extern "C" void kernel_launch(void* const* d_in, const int* in_sizes, int n_in,
                              void* d_out, int out_size, void* d_ws, size_t ws_size,
                              hipStream_t stream) {
    const float* x  = (const float*)d_in[0];   // [4,4096,1024]
    const float* W  = (const float*)d_in[1];   // [2048,2048]
    const float* bg = (const float*)d_in[2];   // [2048]
    float* out = (float*)d_out;                // [BLD gating | BLD avg]
    float* avg = out + (size_t)BLD;

    char* ws = (char*)d_ws;
    unsigned short* Abf = (unsigned short*)(ws);                      // 64 MB  [16384 x 2048] bf16 (K-interleaved)
    unsigned short* Wbf = (unsigned short*)(ws + (size_t)67108864);   //  8 MB  [2048 x 2048] bf16 (K-interleaved)
    float*          prt = (float*)(ws + (size_t)75497472);            // 512 KB [512 x 256] chunk sums
    unsigned int*   flg = (unsigned int*)(ws + (size_t)76021760);     //   2 KB [512] lookback flags (poison != MAGIC)

    scan_conv<<<dim3(2560), dim3(256), 0, stream>>>(
        x, W, avg, (unsigned int*)Abf, (ushort4*)Wbf, prt, flg);
    gemm_gated<<<dim3(1024), dim3(256), 0, stream>>>(Abf, Wbf, x, avg, bg, out);
}